// Round 13
// baseline (197.291 us; speedup 1.0000x reference)
//
#include <hip/hip_runtime.h>
#include <math.h>

#define TT  1024
#define BB  2048
#define FF  11
#define PP  256
#define NG  100
#define NCH 32           // chunks over T
#define LCH (TT / NCH)   // 32 steps per chunk
#define JJ  4            // phaseC unroll / prefetch depth

typedef float f32x2 __attribute__((ext_vector_type(2)));

__device__ __forceinline__ float nz(float v) { return (v != v) ? 0.f : v; }

// Branch-free erf, Abramowitz-Stegun 7.1.26, |err| <= 1.5e-7 (abs).
__device__ __forceinline__ float erf_fast(float x) {
    float ax = fabsf(x);
    float t  = __builtin_amdgcn_rcpf(fmaf(0.3275911f, ax, 1.f));
    float y  = fmaf(fmaf(fmaf(fmaf(1.061405429f, t, -1.453152027f), t,
                              1.421413741f), t, -0.284496736f), t, 0.254829592f);
    y *= t;
    float r = fmaf(-y, __expf(-ax * ax), 1.f);
    return copysignf(r, x);
}

// q coefficients for one (t,b) record. Returns (q0, q1, B0=beta*pi1n, B1=beta*pi0n).
__device__ __forceinline__ float4 q_from_rec(
    float a0, float a1, float r0, float r1, float cdc, float cdn,
    float beta, float inv_s)
{
    float u = 0.5f * (1.f + erf_fast((0.0f  - cdc) * inv_s));
    float v = 0.5f * (1.f + erf_fast((-0.1f - cdc) * inv_s));
    float w = 0.5f * (1.f + erf_fast((0.1f  - cdc) * inv_s));
    float inv = 1.f / fmaxf(w - v, 1e-10f);
    float pi0 = fminf(fmaxf((u - v) * inv, 0.f), 1.f);
    float pi1 = fminf(fmaxf((w - u) * inv, 0.f), 1.f);

    u = 0.5f * (1.f + erf_fast((0.0f  - cdn) * inv_s));
    v = 0.5f * (1.f + erf_fast((-0.1f - cdn) * inv_s));
    w = 0.5f * (1.f + erf_fast((0.1f  - cdn) * inv_s));
    inv = 1.f / fmaxf(w - v, 1e-10f);
    float pi0n = fminf(fmaxf((u - v) * inv, 0.f), 1.f);
    float pi1n = fminf(fmaxf((w - u) * inv, 0.f), 1.f);

    float rs = r0 * a0 + r1 * a1;
    float r  = (a0 >= a1) ? rs : 1.f - rs;      // argmax tie -> index 0
    float q0 = pi1 * r + pi0 * (1.f - r);
    float q1 = (2.f * r - 1.f) * (pi0 - pi1);
    if (!((a0 + a1) > 0.f)) { q0 = 1.f; q1 = 0.f; }
    return make_float4(q0, q1, beta * pi1n, beta * pi0n);
}

// be' = max(be*u, 1e-30) with u = q0+q1*p <= 1 (convex combo of clamped
// probs, mod 2 ulp): over a chunk, be_out = max(be_in * prod(u), 1e-30).
// Only U = prod(u) needs storing (validated R11/R12).

// ---------------- Phase Aq: pipelined sub-slab staging + per-chunk U --------
// Wave W: b-octet wg = W & 255, chunk c = W >> 8; g = lane&7 (batch),
// sl = lane>>3 (step-in-block). The 32-t chunk is processed in 4 sub-slabs
// of 8 t (176 float4 = 2816 B/wave); the next sub-slab is prefetched into
// registers during the current one's compute (software pipeline). No
// __syncthreads — all LDS is per-wave, only wave_barriers. LDS/block
// 13.3 KB; __launch_bounds__(256,6) targets ~6 waves/SIMD.
__global__ __launch_bounds__(256, 6) void phaseAq_kernel(
    const float* __restrict__ x, const float* __restrict__ beta_raw,
    const float* __restrict__ sigma_raw, float4* __restrict__ QC,
    float* __restrict__ UC)
{
    __shared__ float  sx[4][8 * 88];             // 2816 B per wave: 8t x 8b x 11f
    __shared__ float2 sq[4][64];                 // q exchange per wave
    const int lane = threadIdx.x & 63;
    const int wib  = threadIdx.x >> 6;
    const int W    = blockIdx.x * 4 + wib;       // 0..8191
    const int wg   = W & 255;                    // b-octet
    const int c    = W >> 8;                     // chunk 0..31
    const int g    = lane & 7;
    const int sl   = lane >> 3;
    const int b    = wg * 8 + g;
    const int t0   = c * LCH;
    float*  sxw = sx[wib];
    float2* sqw = sq[wib];

    // staging index split: idx in 0..175 -> row=idx/22, col=idx-22*row
    const int r0i = lane / 22,         c0i = lane - r0i * 22;
    const int r1i = (lane + 64) / 22,  c1i = (lane + 64) - r1i * 22;
    const int r2i = (lane + 128) / 22, c2i = (lane + 128) - r2i * 22; // lane<48
    const float4* x4 = (const float4*)x;         // row t base: t*5632 float4
    const size_t base = (size_t)t0 * 5632 + (size_t)wg * 22;

    // prefetch sub-slab 0
    float4 pf0 = x4[base + (size_t)r0i * 5632 + c0i];
    float4 pf1 = x4[base + (size_t)r1i * 5632 + c1i];
    float4 pf2;
    if (lane < 48) pf2 = x4[base + (size_t)r2i * 5632 + c2i];

    // per-b participant params (8x redundant across sl-lanes; coalesced)
    int pid = (int)nz(x[(size_t)b * FF + 10]);
    pid = pid < 0 ? 0 : (pid > PP - 1 ? PP - 1 : pid);
    float br = beta_raw[pid];
    float sr = sigma_raw[pid];
    float sp   = fmaxf(br, 0.f) + log1pf(__expf(-fabsf(br)));
    float beta = fminf(fmaxf(sp + 1.f, 1.f), 25.f);
    float sig  = fminf(fmaxf(__builtin_amdgcn_rcpf(1.f + __expf(-sr)) * 0.09f + 0.01f,
                             0.01f), 0.1f);
    float inv_s = 1.f / (sig * 1.41421356237309505f);

    f32x2 p[7];
    #pragma unroll
    for (int k = 0; k < 7; ++k)
        p[k] = (f32x2){ (float)(sl + 16 * k)     * (1.f / 99.f),
                        (float)(sl + 16 * k + 8) * (1.f / 99.f) };

    f32x2 U[7];
    #pragma unroll
    for (int k = 0; k < 7; ++k) U[k] = (f32x2){1.f, 1.f};

    float4* s4 = (float4*)sxw;
    #pragma unroll
    for (int tb = 0; tb < 4; ++tb) {
        // commit prefetched sub-slab to LDS (waits vmcnt on pf regs)
        s4[lane]      = pf0;
        s4[lane + 64] = pf1;
        if (lane < 48) s4[lane + 128] = pf2;
        __builtin_amdgcn_wave_barrier();
        // issue next sub-slab's loads; they fly during this block's compute
        if (tb < 3) {
            const size_t nb = base + (size_t)((tb + 1) * 8) * 5632;
            pf0 = x4[nb + (size_t)r0i * 5632 + c0i];
            pf1 = x4[nb + (size_t)r1i * 5632 + c1i];
            if (lane < 48) pf2 = x4[nb + (size_t)r2i * 5632 + c2i];
        }
        // own record from LDS: row sl, record g (stride 11: light aliasing)
        const float* rec = sxw + sl * 88 + g * 11;
        float a0 = nz(rec[0]), a1 = nz(rec[1]), r0 = nz(rec[2]),
              r1 = nz(rec[3]), dc = nz(rec[4]), dn = nz(rec[5]);
        float4 qc = q_from_rec(a0, a1, r0, r1, dc, dn, beta, inv_s);
        QC[(size_t)(t0 + tb * 8 + sl) * BB + b] = qc;   // 128B contig / sl-group

        // wave-synchronous q exchange (pattern validated R11/R12)
        sqw[sl * 8 + g] = make_float2(qc.x, qc.y);
        __builtin_amdgcn_wave_barrier();
        #pragma unroll
        for (int j = 0; j < 8; ++j) {
            float2 qj = sqw[j * 8 + g];          // broadcast reads, no conflict
            f32x2 qx = { qj.x, qj.x }, qy = { qj.y, qj.y };
            #pragma unroll
            for (int k = 0; k < 7; ++k) {
                f32x2 u = qy * p[k] + qx;        // v_pk_fma_f32
                U[k] *= u;                       // v_pk_mul_f32
            }
        }
        __builtin_amdgcn_wave_barrier();         // slab+sq reads done before overwrite
    }

    // UC layout [c][i][b]: consecutive lanes (b) -> coalesced float stores
    float* dst = UC + (size_t)c * (NG * BB) + b;
    #pragma unroll
    for (int k = 0; k < 6; ++k) {
        dst[(size_t)(sl + 16 * k) * BB]     = U[k].x;
        dst[(size_t)(sl + 16 * k + 8) * BB] = U[k].y;
    }
    if (sl < 4) dst[(size_t)(sl + 96) * BB] = U[6].x;
}

// ---------------- Phase B: 32-step scan over chunks per (i,b) ----------------
// flat = i*BB + b (layout [c][i][b]); elementwise over flat, coalesced.
__global__ __launch_bounds__(256) void phaseB_kernel(
    const float* __restrict__ UC, float* __restrict__ BE)
{
    const int flat = blockIdx.x * 256 + threadIdx.x;
    float be = 1.f;
    #pragma unroll
    for (int c = 0; c < NCH; ++c) {
        BE[(size_t)c * (BB * NG) + flat] = be;
        float u = UC[(size_t)c * (BB * NG) + flat];
        be = fmaxf(be * u, 1e-30f);              // constant-floor composition
    }
}

// ---------------- Phase C: parallel chunk re-walk, logits + carry ------------
// 8 lanes per b (sl = lane&7 -> contiguous groups, DPP-friendly), 8 b per wave.
__global__ __launch_bounds__(256) void phaseC_kernel(
    const float4* __restrict__ QC, const float* __restrict__ BE,
    float* __restrict__ out)
{
    const int lane = threadIdx.x & 63;
    const int wib  = threadIdx.x >> 6;
    const int W    = blockIdx.x * 4 + wib;       // 0..8191
    const int wg   = W & 255;                    // b-octet
    const int c    = W >> 8;                     // chunk 0..31
    const int sl   = lane & 7;
    const int g    = lane >> 3;
    const int b    = wg * 8 + g;
    const int t0   = c * LCH;

    f32x2 p[7];
    #pragma unroll
    for (int k = 0; k < 7; ++k)
        p[k] = (f32x2){ (float)(sl + 16 * k)     * (1.f / 99.f),
                        (float)(sl + 16 * k + 8) * (1.f / 99.f) };
    const f32x2 clA = { 1e-30f, 1e-30f };
    const f32x2 cl6 = { (sl < 4) ? 1e-30f : 0.f, 0.f };   // pair 6: i=96..111

    // chunk-entry beliefs from BE[c][i][b] (13 scattered loads, once per wave)
    const float* ebase = BE + (size_t)c * (BB * NG) + b;
    f32x2 be[7];
    #pragma unroll
    for (int k = 0; k < 6; ++k)
        be[k] = (f32x2){ ebase[(size_t)(sl + 16 * k) * BB],
                         ebase[(size_t)(sl + 16 * k + 8) * BB] };
    be[6] = (f32x2){ (sl < 4) ? ebase[(size_t)(sl + 96) * BB] : 0.f, 0.f };

    const char* QCb = (const char*)QC;
    char* outb = (char*)out;
    unsigned off  = ((unsigned)t0 * BB + (unsigned)b) * 16u;          // QC bytes
    unsigned soff = ((unsigned)t0 * (2 * BB) + 2 * (unsigned)b) * 4u; // out bytes

    float4 pre[JJ];
    #pragma unroll
    for (int j = 0; j < JJ; ++j)
        pre[j] = *(const float4*)(QCb + (off + (unsigned)j * (BB * 16u)));
    off += JJ * (BB * 16u);

    for (int tt = 0; tt < LCH; tt += JJ) {
        float S[JJ], Sp[JJ], Zv[JJ], Wv[JJ];
        #pragma unroll
        for (int j = 0; j < JJ; ++j) {
            float4 q = pre[j];
            // overrun prefetch (last iter, c=31) lands in UC region: never used
            pre[j] = *(const float4*)(QCb + (off + (unsigned)j * (BB * 16u)));
            f32x2 qx = { q.x, q.x }, qy = { q.y, q.y };
            #pragma unroll
            for (int k = 0; k < 7; ++k) {
                f32x2 u = qy * p[k] + qx;
                be[k] = __builtin_elementwise_max(be[k] * u,
                                                  (k == 6) ? cl6 : clA);
            }
            f32x2 sA = ((be[0] + be[1]) + (be[2] + be[3]))
                     + ((be[4] + be[5]) + be[6]);
            S[j] = sA.x + sA.y;
            f32x2 a1 = be[0] * p[0], a2 = be[1] * p[1];
            a1 = be[2] * p[2] + a1;  a2 = be[3] * p[3] + a2;
            a1 = be[4] * p[4] + a1;  a2 = be[5] * p[5] + a2;
            a1 = be[6] * p[6] + a1;
            f32x2 aa = a1 + a2;
            Sp[j] = aa.x + aa.y;
            Zv[j] = q.z;
            Wv[j] = q.w;
        }
        off += JJ * (BB * 16u);
        #pragma unroll
        for (int j = 0; j < JJ; ++j) {
            // 8-lane butterfly sum (pure VALU DPP)
            float st = S[j], sr = Sp[j];
            {
                int t;
                t = __builtin_amdgcn_update_dpp(0, __float_as_int(st), 0xB1, 0xF, 0xF, true);
                st += __int_as_float(t);
                t = __builtin_amdgcn_update_dpp(0, __float_as_int(sr), 0xB1, 0xF, 0xF, true);
                sr += __int_as_float(t);
                t = __builtin_amdgcn_update_dpp(0, __float_as_int(st), 0x4E, 0xF, 0xF, true);
                st += __int_as_float(t);
                t = __builtin_amdgcn_update_dpp(0, __float_as_int(sr), 0x4E, 0xF, 0xF, true);
                sr += __int_as_float(t);
                t = __builtin_amdgcn_update_dpp(0, __float_as_int(st), 0x141, 0xF, 0xF, true);
                st += __int_as_float(t);
                t = __builtin_amdgcn_update_dpp(0, __float_as_int(sr), 0x141, 0xF, 0xF, true);
                sr += __int_as_float(t);
            }
            float E  = sr * __builtin_amdgcn_rcpf(st);
            float A  = Wv[j] - Zv[j];
            float l0 = fmaf(A, E, Zv[j]);
            float l1 = fmaf(-A, E, Wv[j]);
            if (sl == 0)   // 8 lanes store 8B each; octet is 64B contiguous
                *(float2*)(outb + (soff + (unsigned)j * (2 * BB * 4u))) =
                    make_float2(l0, l1);
        }
        soff += JJ * (2 * BB * 4u);
    }

    if (c == NCH - 1) {   // final belief carry: out[T*B*2 + b*100 + i]
        float* bel = out + (size_t)TT * BB * 2 + (size_t)b * NG;
        #pragma unroll
        for (int k = 0; k < 6; ++k) {
            bel[sl + 16 * k]     = be[k].x;
            bel[sl + 16 * k + 8] = be[k].y;
        }
        if (sl < 4) bel[sl + 96] = be[6].x;
    }
}

extern "C" void kernel_launch(void* const* d_in, const int* in_sizes, int n_in,
                              void* d_out, int out_size, void* d_ws, size_t ws_size,
                              hipStream_t stream)
{
    const float* x         = (const float*)d_in[0];
    const float* beta_raw  = (const float*)d_in[1];
    const float* sigma_raw = (const float*)d_in[2];
    float* out = (float*)d_out;

    // workspace: QC (32 MiB) | UC (26.2 MB) | BE (26.2 MB)  ~= 85 MB
    char* ws = (char*)d_ws;
    float4* QC = (float4*)ws;
    float*  UC = (float*)(ws + (size_t)TT * BB * 16);
    float*  BE = (float*)(ws + (size_t)TT * BB * 16 + (size_t)NCH * BB * NG * 4);

    phaseAq_kernel<<<(BB / 8) * NCH / 4, 256, 0, stream>>>(x, beta_raw, sigma_raw, QC, UC);
    phaseB_kernel<<<(BB * NG) / 256, 256, 0, stream>>>(UC, BE);
    phaseC_kernel<<<(BB / 8) * NCH / 4, 256, 0, stream>>>(QC, BE, out);
}

// Round 15
// 192.522 us; speedup vs baseline: 1.0248x; 1.0248x over previous
//
#include <hip/hip_runtime.h>
#include <math.h>

#define TT  1024
#define BB  2048
#define FF  11
#define PP  256
#define NG  100
#define NCH 32           // chunks over T
#define LCH (TT / NCH)   // 32 steps per chunk
#define JJ  4            // phaseC unroll / prefetch depth

typedef float f32x2 __attribute__((ext_vector_type(2)));

__device__ __forceinline__ float nz(float v) { return (v != v) ? 0.f : v; }

// Branch-free erf, Abramowitz-Stegun 7.1.26, |err| <= 1.5e-7 (abs).
__device__ __forceinline__ float erf_fast(float x) {
    float ax = fabsf(x);
    float t  = __builtin_amdgcn_rcpf(fmaf(0.3275911f, ax, 1.f));
    float y  = fmaf(fmaf(fmaf(fmaf(1.061405429f, t, -1.453152027f), t,
                              1.421413741f), t, -0.284496736f), t, 0.254829592f);
    y *= t;
    float r = fmaf(-y, __expf(-ax * ax), 1.f);
    return copysignf(r, x);
}

// q coefficients for one (t,b) record. Returns (q0, q1, B0=beta*pi1n, B1=beta*pi0n).
__device__ __forceinline__ float4 q_from_rec(
    float a0, float a1, float r0, float r1, float cdc, float cdn,
    float beta, float inv_s)
{
    float u = 0.5f * (1.f + erf_fast((0.0f  - cdc) * inv_s));
    float v = 0.5f * (1.f + erf_fast((-0.1f - cdc) * inv_s));
    float w = 0.5f * (1.f + erf_fast((0.1f  - cdc) * inv_s));
    float inv = 1.f / fmaxf(w - v, 1e-10f);
    float pi0 = fminf(fmaxf((u - v) * inv, 0.f), 1.f);
    float pi1 = fminf(fmaxf((w - u) * inv, 0.f), 1.f);

    u = 0.5f * (1.f + erf_fast((0.0f  - cdn) * inv_s));
    v = 0.5f * (1.f + erf_fast((-0.1f - cdn) * inv_s));
    w = 0.5f * (1.f + erf_fast((0.1f  - cdn) * inv_s));
    inv = 1.f / fmaxf(w - v, 1e-10f);
    float pi0n = fminf(fmaxf((u - v) * inv, 0.f), 1.f);
    float pi1n = fminf(fmaxf((w - u) * inv, 0.f), 1.f);

    float rs = r0 * a0 + r1 * a1;
    float r  = (a0 >= a1) ? rs : 1.f - rs;      // argmax tie -> index 0
    float q0 = pi1 * r + pi0 * (1.f - r);
    float q1 = (2.f * r - 1.f) * (pi0 - pi1);
    if (!((a0 + a1) > 0.f)) { q0 = 1.f; q1 = 0.f; }
    return make_float4(q0, q1, beta * pi1n, beta * pi0n);
}

// be' = max(be*u, 1e-30) with u = q0+q1*p <= 1 (convex combo of clamped
// probs, mod 2 ulp): over a chunk, be_out = max(be_in * prod(u), 1e-30).
// Only U = prod(u) needs storing (validated R11/R12).

// ---------------- Phase Aq: LDS-staged coeff-compute + per-chunk U ----------
// Wave W: b-octet wg = W & 255, chunk c = W >> 8. Lane (g = lane&7 = batch,
// sl = lane>>3 = step-in-block). The wave's whole x-slab (32 t x 8 b x 11 f
// = 11 KB) is staged into LDS with 11 coalesced float4 loads/lane (deep MLP),
// then the record reads / q-compute / exchange run entirely out of LDS.
// (R13's sub-slab pipeline variant regressed: 4 vmcnt drain points vs 1.)
__global__ __launch_bounds__(256) void phaseAq_kernel(
    const float* __restrict__ x, const float* __restrict__ beta_raw,
    const float* __restrict__ sigma_raw, float4* __restrict__ QC,
    float* __restrict__ UC)
{
    __shared__ float  sx[4][LCH * 88];           // 45056 B: x slab per wave
    __shared__ float2 sq[4][64];                 // 2048 B: q exchange per wave
    const int lane = threadIdx.x & 63;
    const int wib  = threadIdx.x >> 6;
    const int W    = blockIdx.x * 4 + wib;       // 0..8191
    const int wg   = W & 255;                    // b-octet
    const int c    = W >> 8;                     // chunk 0..31
    const int g    = lane & 7;
    const int sl   = lane >> 3;
    const int b    = wg * 8 + g;
    const int t0   = c * LCH;
    float*  sxw = sx[wib];
    float2* sqw = sq[wib];

    // ---- stage chunk x-slab: 32 rows x 88 floats = 704 float4, coalesced ----
    {
        const float4* x4 = (const float4*)x;     // row t: base (t*BB*FF)/4 = t*5632
        float4* s4 = (float4*)sxw;
        #pragma unroll
        for (int j = 0; j < 11; ++j) {
            int idx = lane + 64 * j;             // 0..703
            int row = idx / 22;                  // const-div -> magic mul
            int col = idx - row * 22;
            s4[idx] = x4[(size_t)(t0 + row) * 5632 + wg * 22 + col];
        }
    }

    // per-b participant params (overlaps staging loads; 8x redundant, cheap)
    int pid = (int)nz(x[(size_t)b * FF + 10]);
    pid = pid < 0 ? 0 : (pid > PP - 1 ? PP - 1 : pid);
    float br = beta_raw[pid];
    float sr = sigma_raw[pid];
    float sp   = fmaxf(br, 0.f) + log1pf(__expf(-fabsf(br)));
    float beta = fminf(fmaxf(sp + 1.f, 1.f), 25.f);
    float sig  = fminf(fmaxf(__builtin_amdgcn_rcpf(1.f + __expf(-sr)) * 0.09f + 0.01f,
                             0.01f), 0.1f);
    float inv_s = 1.f / (sig * 1.41421356237309505f);

    f32x2 p[7];
    #pragma unroll
    for (int k = 0; k < 7; ++k)
        p[k] = (f32x2){ (float)(sl + 16 * k)     * (1.f / 99.f),
                        (float)(sl + 16 * k + 8) * (1.f / 99.f) };

    f32x2 U[7];
    #pragma unroll
    for (int k = 0; k < 7; ++k) U[k] = (f32x2){1.f, 1.f};

    __syncthreads();                             // staging visible to all lanes

    for (int tt = 0; tt < LCH; tt += 8) {
        // own record from LDS: row tt+sl, record g (2-way bank alias = free)
        const float* rec = sxw + (tt + sl) * 88 + g * 11;
        float a0 = nz(rec[0]), a1 = nz(rec[1]), r0 = nz(rec[2]),
              r1 = nz(rec[3]), dc = nz(rec[4]), dn = nz(rec[5]);
        float4 qc = q_from_rec(a0, a1, r0, r1, dc, dn, beta, inv_s);
        QC[(size_t)(t0 + tt + sl) * BB + b] = qc;    // 128B contig per sl-group

        // wave-synchronous q exchange (pattern validated R11)
        sqw[sl * 8 + g] = make_float2(qc.x, qc.y);
        __builtin_amdgcn_wave_barrier();
        #pragma unroll
        for (int j = 0; j < 8; ++j) {
            float2 qj = sqw[j * 8 + g];          // 8 addrs, broadcast reads
            f32x2 qx = { qj.x, qj.x }, qy = { qj.y, qj.y };
            #pragma unroll
            for (int k = 0; k < 7; ++k) {
                f32x2 u = qy * p[k] + qx;        // v_pk_fma_f32
                U[k] *= u;                       // v_pk_mul_f32
            }
        }
        __builtin_amdgcn_wave_barrier();         // reads before next overwrite
    }

    // UC layout [c][i][b]: consecutive lanes (b) -> coalesced float stores
    float* dst = UC + (size_t)c * (NG * BB) + b;
    #pragma unroll
    for (int k = 0; k < 6; ++k) {
        dst[(size_t)(sl + 16 * k) * BB]     = U[k].x;
        dst[(size_t)(sl + 16 * k + 8) * BB] = U[k].y;
    }
    if (sl < 4) dst[(size_t)(sl + 96) * BB] = U[6].x;
}

// ---------------- Phase B: 32-step scan over chunks per (i,b) ----------------
// flat = i*BB + b (layout [c][i][b]); elementwise over flat, coalesced.
__global__ __launch_bounds__(256) void phaseB_kernel(
    const float* __restrict__ UC, float* __restrict__ BE)
{
    const int flat = blockIdx.x * 256 + threadIdx.x;
    float be = 1.f;
    #pragma unroll
    for (int c = 0; c < NCH; ++c) {
        BE[(size_t)c * (BB * NG) + flat] = be;
        float u = UC[(size_t)c * (BB * NG) + flat];
        be = fmaxf(be * u, 1e-30f);              // constant-floor composition
    }
}

// ---------------- Phase C: parallel chunk re-walk, logits + carry ------------
// 8 lanes per b (sl = lane&7 -> contiguous groups, DPP-friendly), 8 b per wave.
__global__ __launch_bounds__(256) void phaseC_kernel(
    const float4* __restrict__ QC, const float* __restrict__ BE,
    float* __restrict__ out)
{
    const int lane = threadIdx.x & 63;
    const int wib  = threadIdx.x >> 6;
    const int W    = blockIdx.x * 4 + wib;       // 0..8191
    const int wg   = W & 255;                    // b-octet
    const int c    = W >> 8;                     // chunk 0..31
    const int sl   = lane & 7;
    const int g    = lane >> 3;
    const int b    = wg * 8 + g;
    const int t0   = c * LCH;

    f32x2 p[7];
    #pragma unroll
    for (int k = 0; k < 7; ++k)
        p[k] = (f32x2){ (float)(sl + 16 * k)     * (1.f / 99.f),
                        (float)(sl + 16 * k + 8) * (1.f / 99.f) };
    const f32x2 clA = { 1e-30f, 1e-30f };
    const f32x2 cl6 = { (sl < 4) ? 1e-30f : 0.f, 0.f };   // pair 6: i=96..111

    // chunk-entry beliefs from BE[c][i][b] (13 scattered loads, once per wave)
    const float* ebase = BE + (size_t)c * (BB * NG) + b;
    f32x2 be[7];
    #pragma unroll
    for (int k = 0; k < 6; ++k)
        be[k] = (f32x2){ ebase[(size_t)(sl + 16 * k) * BB],
                         ebase[(size_t)(sl + 16 * k + 8) * BB] };
    be[6] = (f32x2){ (sl < 4) ? ebase[(size_t)(sl + 96) * BB] : 0.f, 0.f };

    const char* QCb = (const char*)QC;
    char* outb = (char*)out;
    unsigned off  = ((unsigned)t0 * BB + (unsigned)b) * 16u;          // QC bytes
    unsigned soff = ((unsigned)t0 * (2 * BB) + 2 * (unsigned)b) * 4u; // out bytes

    float4 pre[JJ];
    #pragma unroll
    for (int j = 0; j < JJ; ++j)
        pre[j] = *(const float4*)(QCb + (off + (unsigned)j * (BB * 16u)));
    off += JJ * (BB * 16u);

    for (int tt = 0; tt < LCH; tt += JJ) {
        float S[JJ], Sp[JJ], Zv[JJ], Wv[JJ];
        #pragma unroll
        for (int j = 0; j < JJ; ++j) {
            float4 q = pre[j];
            // overrun prefetch (last iter, c=31) lands in UC region: never used
            pre[j] = *(const float4*)(QCb + (off + (unsigned)j * (BB * 16u)));
            f32x2 qx = { q.x, q.x }, qy = { q.y, q.y };
            #pragma unroll
            for (int k = 0; k < 7; ++k) {
                f32x2 u = qy * p[k] + qx;
                be[k] = __builtin_elementwise_max(be[k] * u,
                                                  (k == 6) ? cl6 : clA);
            }
            f32x2 sA = ((be[0] + be[1]) + (be[2] + be[3]))
                     + ((be[4] + be[5]) + be[6]);
            S[j] = sA.x + sA.y;
            f32x2 a1 = be[0] * p[0], a2 = be[1] * p[1];
            a1 = be[2] * p[2] + a1;  a2 = be[3] * p[3] + a2;
            a1 = be[4] * p[4] + a1;  a2 = be[5] * p[5] + a2;
            a1 = be[6] * p[6] + a1;
            f32x2 aa = a1 + a2;
            Sp[j] = aa.x + aa.y;
            Zv[j] = q.z;
            Wv[j] = q.w;
        }
        off += JJ * (BB * 16u);
        #pragma unroll
        for (int j = 0; j < JJ; ++j) {
            // 8-lane butterfly sum (pure VALU DPP)
            float st = S[j], sr = Sp[j];
            {
                int t;
                t = __builtin_amdgcn_update_dpp(0, __float_as_int(st), 0xB1, 0xF, 0xF, true);
                st += __int_as_float(t);
                t = __builtin_amdgcn_update_dpp(0, __float_as_int(sr), 0xB1, 0xF, 0xF, true);
                sr += __int_as_float(t);
                t = __builtin_amdgcn_update_dpp(0, __float_as_int(st), 0x4E, 0xF, 0xF, true);
                st += __int_as_float(t);
                t = __builtin_amdgcn_update_dpp(0, __float_as_int(sr), 0x4E, 0xF, 0xF, true);
                sr += __int_as_float(t);
                t = __builtin_amdgcn_update_dpp(0, __float_as_int(st), 0x141, 0xF, 0xF, true);
                st += __int_as_float(t);
                t = __builtin_amdgcn_update_dpp(0, __float_as_int(sr), 0x141, 0xF, 0xF, true);
                sr += __int_as_float(t);
            }
            float E  = sr * __builtin_amdgcn_rcpf(st);
            float A  = Wv[j] - Zv[j];
            float l0 = fmaf(A, E, Zv[j]);
            float l1 = fmaf(-A, E, Wv[j]);
            if (sl == 0)   // 8 lanes store 8B each; octet is 64B contiguous
                *(float2*)(outb + (soff + (unsigned)j * (2 * BB * 4u))) =
                    make_float2(l0, l1);
        }
        soff += JJ * (2 * BB * 4u);
    }

    if (c == NCH - 1) {   // final belief carry: out[T*B*2 + b*100 + i]
        float* bel = out + (size_t)TT * BB * 2 + (size_t)b * NG;
        #pragma unroll
        for (int k = 0; k < 6; ++k) {
            bel[sl + 16 * k]     = be[k].x;
            bel[sl + 16 * k + 8] = be[k].y;
        }
        if (sl < 4) bel[sl + 96] = be[6].x;
    }
}

extern "C" void kernel_launch(void* const* d_in, const int* in_sizes, int n_in,
                              void* d_out, int out_size, void* d_ws, size_t ws_size,
                              hipStream_t stream)
{
    const float* x         = (const float*)d_in[0];
    const float* beta_raw  = (const float*)d_in[1];
    const float* sigma_raw = (const float*)d_in[2];
    float* out = (float*)d_out;

    // workspace: QC (32 MiB) | UC (26.2 MB) | BE (26.2 MB)  ~= 85 MB
    char* ws = (char*)d_ws;
    float4* QC = (float4*)ws;
    float*  UC = (float*)(ws + (size_t)TT * BB * 16);
    float*  BE = (float*)(ws + (size_t)TT * BB * 16 + (size_t)NCH * BB * NG * 4);

    phaseAq_kernel<<<(BB / 8) * NCH / 4, 256, 0, stream>>>(x, beta_raw, sigma_raw, QC, UC);
    phaseB_kernel<<<(BB * NG) / 256, 256, 0, stream>>>(UC, BE);
    phaseC_kernel<<<(BB / 8) * NCH / 4, 256, 0, stream>>>(QC, BE, out);
}